// Round 2
// baseline (288.622 us; speedup 1.0000x reference)
//
#include <hip/hip_runtime.h>

#define B_BATCH 128
#define N_RX 34
#define IMG 512
#define PLANE (IMG * IMG)            // 262144 floats per plane
#define REGION (2 * PLANE)           // 524288 floats per batch (2 planes)
#define THREADS 256
#define FLOATS_PER_THREAD 16         // 4 x float4
#define FLOATS_PER_BLOCK (THREADS * FLOATS_PER_THREAD)   // 4096
#define BLOCKS_PER_BATCH (REGION / FLOATS_PER_BLOCK)     // 128
#define N_ENT (2 * N_RX)             // 68 scatter entries per batch

typedef float vfloat4 __attribute__((ext_vector_type(4)));

// One block fills a contiguous 4096-float chunk of one batch's 2-plane
// region with zeros + any scatter points landing in that chunk. Entry list
// is built per block (redundant but trivially cheap) and filtered by thread
// 0 IN ORDER (plane0 r=0..33, then plane1 r=0..33) so duplicate coords
// resolve last-write-wins exactly like the numpy reference.
__global__ __launch_bounds__(THREADS)
void Vec2Im_fused_kernel(const float4* __restrict__ xv,
                         const float* __restrict__ dw,
                         const float* __restrict__ db,
                         const float* __restrict__ cw,
                         const float* __restrict__ cb,
                         float* __restrict__ out) {
    __shared__ int   s_pos[N_ENT];
    __shared__ float s_val[N_ENT];
    __shared__ int   s_fpos[N_ENT];
    __shared__ float s_fval[N_ENT];
    __shared__ int   s_cnt;

    const int b     = blockIdx.x >> 7;      // / BLOCKS_PER_BATCH
    const int chunk = blockIdx.x & (BLOCKS_PER_BATCH - 1);
    const int t     = threadIdx.x;

    if (t < N_RX) {
        float4 v = xv[(size_t)b * N_RX + t];
        float raw  = v.x;
        float mask = (raw != 0.0f) ? 1.0f : 0.0f;
        float p = raw * dw[t] + mask * db[t];
        int cat = (int)v.w;                  // exact-int float, truncation ok
        p = p * cw[cat] + mask * cb[cat];
        int xx = (int)rintf(v.y);
        int yy = (int)rintf(v.z);
        int off = yy * IMG + xx;
        s_pos[t]        = off;               s_val[t]        = p;    // plane 0
        s_pos[N_RX + t] = off + PLANE;       s_val[N_RX + t] = raw;  // plane 1
    }
    __syncthreads();

    // Serial in-order filter: cheap (68 iters, once per block), preserves
    // the write order needed for duplicate-coordinate last-write-wins.
    if (t == 0) {
        const int lo = chunk * FLOATS_PER_BLOCK;
        const int hi = lo + FLOATS_PER_BLOCK;
        int c = 0;
        for (int i = 0; i < N_ENT; ++i) {
            int p = s_pos[i];
            if (p >= lo && p < hi) { s_fpos[c] = p - lo; s_fval[c] = s_val[i]; ++c; }
        }
        s_cnt = c;
    }
    __syncthreads();

    vfloat4 v0 = {0.f, 0.f, 0.f, 0.f};
    vfloat4 v1 = {0.f, 0.f, 0.f, 0.f};
    vfloat4 v2 = {0.f, 0.f, 0.f, 0.f};
    vfloat4 v3 = {0.f, 0.f, 0.f, 0.f};

    // Interleaved mapping for coalescing: float4 index f (0..1023 within the
    // chunk) belongs to thread f&255, vector slot f>>8. Avg s_cnt ~0.5, so
    // this loop body almost never executes; all indices below are constants
    // (pure cndmask, no scratch spill).
    const int cnt = s_cnt;
    for (int i = 0; i < cnt; ++i) {
        int q  = s_fpos[i];
        int f  = q >> 2;
        bool mine = ((f & (THREADS - 1)) == t);
        float vv  = s_fval[i];
        int k  = f >> 8;       // which of the 4 float4s
        int e  = q & 3;        // element within the float4
        if (mine && k == 0) { if (e==0) v0.x=vv; else if (e==1) v0.y=vv; else if (e==2) v0.z=vv; else v0.w=vv; }
        if (mine && k == 1) { if (e==0) v1.x=vv; else if (e==1) v1.y=vv; else if (e==2) v1.z=vv; else v1.w=vv; }
        if (mine && k == 2) { if (e==0) v2.x=vv; else if (e==1) v2.y=vv; else if (e==2) v2.z=vv; else v2.w=vv; }
        if (mine && k == 3) { if (e==0) v3.x=vv; else if (e==1) v3.y=vv; else if (e==2) v3.z=vv; else v3.w=vv; }
    }

    vfloat4* o4 = (vfloat4*)(out + (size_t)b * REGION + (size_t)chunk * FLOATS_PER_BLOCK);
    __builtin_nontemporal_store(v0, o4 + t);
    __builtin_nontemporal_store(v1, o4 + THREADS + t);
    __builtin_nontemporal_store(v2, o4 + 2 * THREADS + t);
    __builtin_nontemporal_store(v3, o4 + 3 * THREADS + t);
}

extern "C" void kernel_launch(void* const* d_in, const int* in_sizes, int n_in,
                              void* d_out, int out_size, void* d_ws, size_t ws_size,
                              hipStream_t stream) {
    const float4* x_vecs          = (const float4*)d_in[0];
    const float* device_weights   = (const float*)d_in[1];
    const float* device_bias      = (const float*)d_in[2];
    const float* category_weights = (const float*)d_in[3];
    const float* category_bias    = (const float*)d_in[4];
    float* out = (float*)d_out;

    // Single fused fill+scatter pass over the 256 MiB output.
    Vec2Im_fused_kernel<<<B_BATCH * BLOCKS_PER_BATCH, THREADS, 0, stream>>>(
        x_vecs, device_weights, device_bias, category_weights, category_bias, out);
}

// Round 3
// 281.053 us; speedup vs baseline: 1.0269x; 1.0269x over previous
//
#include <hip/hip_runtime.h>

#define B_BATCH 128
#define N_RX 34
#define IMG 512
#define PLANE (IMG * IMG)                 // 262144 floats
#define REGION (2 * PLANE)                // 524288 floats per batch
#define THREADS 256
#define F4_PER_THREAD 16                  // 64 floats/thread -> 64 KiB per block
#define FLOATS_PER_BLOCK (THREADS * F4_PER_THREAD * 4)   // 16384
#define BLOCKS_PER_BATCH (REGION / FLOATS_PER_BLOCK)     // 32
#define N_ENT (2 * N_RX)                  // 68

typedef float vfloat4 __attribute__((ext_vector_type(4)));

// ---------------- prep: compute all scatter entries once ----------------
// One block per batch; threads t<N_RX each handle one receiver. Writes
// pos[b][t] / val[b][t] (plane0) and pos[b][34+t] / val[b][34+t] (plane1)
// into workspace. Distinct slots -> no ordering hazard here; the ORDER of
// the entry list (plane0 r=0..33 then plane1 r=0..33) is what encodes
// numpy's last-write-wins, applied serially in the fill kernel's filter.
__global__ __launch_bounds__(64)
void Vec2Im_prep_kernel(const float4* __restrict__ xv,
                        const float* __restrict__ dw,
                        const float* __restrict__ db,
                        const float* __restrict__ cw,
                        const float* __restrict__ cb,
                        int* __restrict__ pos, float* __restrict__ val) {
    const int b = blockIdx.x;
    const int t = threadIdx.x;
    if (t >= N_RX) return;
    float4 v = xv[(size_t)b * N_RX + t];
    float raw  = v.x;
    float mask = (raw != 0.0f) ? 1.0f : 0.0f;
    float p = raw * dw[t] + mask * db[t];
    int cat = (int)v.w;                    // exact-int float; truncation == astype
    p = p * cw[cat] + mask * cb[cat];
    int xx = (int)rintf(v.y);
    int yy = (int)rintf(v.z);
    int off = yy * IMG + xx;
    pos[b * N_ENT + t]        = off;           val[b * N_ENT + t]        = p;
    pos[b * N_ENT + N_RX + t] = off + PLANE;   val[b * N_ENT + N_RX + t] = raw;
}

// ---------------- fill: streaming zero-fill + rare fixup ----------------
// One block owns a contiguous 64 KiB chunk of one batch's region. Entry
// load is two coalesced L2-hot vector loads (no dependent-indexed chain).
// Fast path (~99.6% of blocks): 16 NT float4 stores of a zero register.
__global__ __launch_bounds__(THREADS)
void Vec2Im_fill_kernel(const int* __restrict__ pos,
                        const float* __restrict__ val,
                        float* __restrict__ out) {
    __shared__ int   s_pos[N_ENT];
    __shared__ float s_val[N_ENT];
    __shared__ int   s_fq[N_ENT];
    __shared__ float s_fv[N_ENT];
    __shared__ int   s_cnt;

    const int b     = blockIdx.x / BLOCKS_PER_BATCH;
    const int chunk = blockIdx.x % BLOCKS_PER_BATCH;
    const int t     = threadIdx.x;

    if (t < N_ENT) {
        s_pos[t] = pos[b * N_ENT + t];
        s_val[t] = val[b * N_ENT + t];
    }
    __syncthreads();

    // Serial in-order filter by thread 0 (68 iters, LDS-only): preserves
    // numpy's duplicate-coordinate last-write-wins order.
    if (t == 0) {
        const int lo = chunk * FLOATS_PER_BLOCK;
        int c = 0;
        for (int i = 0; i < N_ENT; ++i) {
            int q = s_pos[i] - lo;
            if ((unsigned)q < (unsigned)FLOATS_PER_BLOCK) {
                s_fq[c] = q; s_fv[c] = s_val[i]; ++c;
            }
        }
        s_cnt = c;
    }
    __syncthreads();

    float* base = out + (size_t)b * REGION + (size_t)chunk * FLOATS_PER_BLOCK;
    vfloat4* o4 = (vfloat4*)base;
    const vfloat4 z = {0.f, 0.f, 0.f, 0.f};
#pragma unroll
    for (int k = 0; k < F4_PER_THREAD; ++k)
        __builtin_nontemporal_store(z, o4 + k * THREADS + t);

    if (s_cnt != 0) {            // uniform branch (LDS value), rare
        __syncthreads();         // drains vmcnt -> zero stores complete first
        if (t == 0) {
            const int c = s_cnt;
            for (int i = 0; i < c; ++i) base[s_fq[i]] = s_fv[i];  // in order
        }
    }
}

extern "C" void kernel_launch(void* const* d_in, const int* in_sizes, int n_in,
                              void* d_out, int out_size, void* d_ws, size_t ws_size,
                              hipStream_t stream) {
    const float4* x_vecs          = (const float4*)d_in[0];
    const float* device_weights   = (const float*)d_in[1];
    const float* device_bias      = (const float*)d_in[2];
    const float* category_weights = (const float*)d_in[3];
    const float* category_bias    = (const float*)d_in[4];
    float* out = (float*)d_out;

    int*   ws_pos = (int*)d_ws;                       // 128*68 ints
    float* ws_val = (float*)((char*)d_ws + B_BATCH * N_ENT * sizeof(int));

    Vec2Im_prep_kernel<<<B_BATCH, 64, 0, stream>>>(
        x_vecs, device_weights, device_bias, category_weights, category_bias,
        ws_pos, ws_val);

    Vec2Im_fill_kernel<<<B_BATCH * BLOCKS_PER_BATCH, THREADS, 0, stream>>>(
        ws_pos, ws_val, out);
}

// Round 4
// 277.069 us; speedup vs baseline: 1.0417x; 1.0144x over previous
//
#include <hip/hip_runtime.h>

#define B_BATCH 128
#define N_RX 34
#define IMG 512
#define PLANE (IMG * IMG)                 // 262144 floats per plane
#define REGION (2 * PLANE)                // 524288 floats per batch
#define THREADS 256
#define F4_PER_THREAD 32                  // 128 floats/thread -> 128 KiB/block
#define FLOATS_PER_BLOCK (THREADS * F4_PER_THREAD * 4)   // 32768
#define BLOCKS_PER_BATCH (REGION / FLOATS_PER_BLOCK)     // 16
#define N_ENT (2 * N_RX)                  // 68

typedef float vfloat4 __attribute__((ext_vector_type(4)));

// Single fused fill+scatter kernel. One block owns a contiguous 128 KiB
// chunk of one batch's 2-plane region.
//
// Ordering of work inside a block (the R2 lesson):
//   1) zero NT stores issue FIRST — no load/barrier dependency ahead of them
//   2) entry computation (dependent x_vec -> cat -> weight[cat] chain)
//      overlaps with the store drain
//   3) ONE __syncthreads(): LDS entries visible to t0 AND all zero stores
//      drained (compiler emits s_waitcnt vmcnt(0) before s_barrier)
//   4) t0 applies in-chunk fixups serially in entry order (plane0 r=0..33,
//      then plane1 r=0..33) -> numpy last-write-wins preserved; same-thread
//      same-address stores are ordered.
__global__ __launch_bounds__(THREADS)
void Vec2Im_fused2_kernel(const float4* __restrict__ xv,
                          const float* __restrict__ dw,
                          const float* __restrict__ db,
                          const float* __restrict__ cw,
                          const float* __restrict__ cb,
                          float* __restrict__ out) {
    __shared__ int   s_pos[N_ENT];
    __shared__ float s_val[N_ENT];

    const int b     = blockIdx.x / BLOCKS_PER_BATCH;
    const int chunk = blockIdx.x % BLOCKS_PER_BATCH;
    const int t     = threadIdx.x;

    float* base = out + (size_t)b * REGION + (size_t)chunk * FLOATS_PER_BLOCK;
    vfloat4* o4 = (vfloat4*)base;
    const vfloat4 z = {0.f, 0.f, 0.f, 0.f};

    // (1) streaming zero fill — the only bulk HBM traffic
#pragma unroll
    for (int k = 0; k < F4_PER_THREAD; ++k)
        __builtin_nontemporal_store(z, o4 + k * THREADS + t);

    // (2) entry computation, overlapped with store drain
    if (t < N_RX) {
        float4 v = xv[(size_t)b * N_RX + t];
        float raw  = v.x;
        float mask = (raw != 0.0f) ? 1.0f : 0.0f;
        float p = raw * dw[t] + mask * db[t];
        int cat = (int)v.w;                  // exact-int float; truncation == astype
        p = p * cw[cat] + mask * cb[cat];
        int xx = (int)rintf(v.y);
        int yy = (int)rintf(v.z);
        int off = yy * IMG + xx;
        s_pos[t]        = off;               s_val[t]        = p;    // plane 0
        s_pos[N_RX + t] = off + PLANE;       s_val[N_RX + t] = raw;  // plane 1
    }

    // (3) one barrier: LDS visibility + zero-store drain
    __syncthreads();

    // (4) rare in-order fixups (~2 per block on average)
    if (t == 0) {
        const int lo = chunk * FLOATS_PER_BLOCK;
        for (int i = 0; i < N_ENT; ++i) {
            int q = s_pos[i] - lo;
            if ((unsigned)q < (unsigned)FLOATS_PER_BLOCK) base[q] = s_val[i];
        }
    }
}

extern "C" void kernel_launch(void* const* d_in, const int* in_sizes, int n_in,
                              void* d_out, int out_size, void* d_ws, size_t ws_size,
                              hipStream_t stream) {
    const float4* x_vecs          = (const float4*)d_in[0];
    const float* device_weights   = (const float*)d_in[1];
    const float* device_bias      = (const float*)d_in[2];
    const float* category_weights = (const float*)d_in[3];
    const float* category_bias    = (const float*)d_in[4];
    float* out = (float*)d_out;

    Vec2Im_fused2_kernel<<<B_BATCH * BLOCKS_PER_BATCH, THREADS, 0, stream>>>(
        x_vecs, device_weights, device_bias, category_weights, category_bias, out);
}